// Round 4
// baseline (790.333 us; speedup 1.0000x reference)
//
#include <hip/hip_runtime.h>

// GCN: h1 = relu(agg(x@W1)); h2 = relu(agg(h1@W2)); out = h2@Wfc + bfc
// out_i = relu( dinv_i * (sum_{j in N(i)} y_j + y_i) + b ),  y = (x@W) * dinv[:,None]
// NO global atomics: owner-computes. 256 workgroups each own 196 nodes, scan the
// packed edge list once (k_build) to extract their private edge set, then the
// two aggregation kernels replay only their private lists (LDS accumulate).
// Round-3 lesson: 800k device-scope atomicAdd ~= 50 us regardless of payload.

#define NWG    256
#define SRANGE 196     // nodes per workgroup; NWG*SRANGE = 50176 >= 50000
#define ECAP   4096    // per-wg edge capacity (mean 3136, sigma ~56 -> 17 sigma)
#define BLK    1024

__global__ __launch_bounds__(256) void k_pack(const int* __restrict__ src,
                                              const int* __restrict__ dst,
                                              unsigned* __restrict__ ep, int E) {
    int e = blockIdx.x * 256 + threadIdx.x;
    if (e < E) ep[e] = ((unsigned)dst[e] << 16) | (unsigned)src[e];
}

// Each wg scans all packed edges; counts degrees for its node range (LDS) and
// compacts its in-range edges to elist[wg*ECAP ...]. No global atomics.
__global__ __launch_bounds__(BLK) void k_build(const unsigned* __restrict__ ep,
                                               unsigned* __restrict__ elist,
                                               int* __restrict__ ecnt,
                                               float* __restrict__ dinv,
                                               int n, int E) {
    __shared__ int lcnt[SRANGE];
    __shared__ int lcur;
    const int tid = threadIdx.x;
    const int A = blockIdx.x * SRANGE;
    for (int i = tid; i < SRANGE; i += BLK) lcnt[i] = 0;
    if (tid == 0) lcur = 0;
    __syncthreads();
    unsigned* const my = elist + (size_t)blockIdx.x * ECAP;
    const int nq = E >> 2;
    const uint4* ep4 = (const uint4*)ep;
    for (int idx = tid; idx < nq; idx += BLK) {
        uint4 q = ep4[idx];
        unsigned uu[4] = {q.x, q.y, q.z, q.w};
#pragma unroll
        for (int c = 0; c < 4; c++) {
            unsigned u = uu[c];
            int ld = (int)(u >> 16) - A;
            if ((unsigned)ld < (unsigned)SRANGE) {
                atomicAdd(&lcnt[ld], 1);              // LDS atomic
                int p = atomicAdd(&lcur, 1);          // LDS atomic
                if (p < ECAP) my[p] = u;
            }
        }
    }
    if (tid == 0) {  // tail if E % 4 != 0
        for (int e = nq << 2; e < E; e++) {
            unsigned u = ep[e];
            int ld = (int)(u >> 16) - A;
            if ((unsigned)ld < (unsigned)SRANGE) {
                atomicAdd(&lcnt[ld], 1);
                int p = atomicAdd(&lcur, 1);
                if (p < ECAP) my[p] = u;
            }
        }
    }
    __syncthreads();
    if (tid == 0) ecnt[blockIdx.x] = lcur < ECAP ? lcur : ECAP;
    for (int i = tid; i < SRANGE; i += BLK) {
        int row = A + i;
        if (row < n) dinv[row] = rsqrtf((float)lcnt[i] + 1.0f);
    }
}

// Y[row][c] = dinv[row] * sum_k X[row][k] * W[k][c];  64 output cols.
template <int K>
__global__ __launch_bounds__(256) void k_gemm(const float* __restrict__ X,
                                              const float* __restrict__ W,
                                              const float* __restrict__ dinv,
                                              float* __restrict__ Y, int n) {
    constexpr int KC = 64;
    constexpr int XS = KC + 4;
    __shared__ float ws[KC * 64];
    __shared__ float xs[64 * XS];
    const int tid = threadIdx.x;
    const int tx = tid & 15;
    const int ty = tid >> 4;
    const int row0 = blockIdx.x * 64;

    float acc[4][4];
#pragma unroll
    for (int r = 0; r < 4; r++)
#pragma unroll
        for (int c = 0; c < 4; c++) acc[r][c] = 0.f;

    for (int kc = 0; kc < K; kc += KC) {
        for (int i = tid; i < KC * 16; i += 256) {
            int kk = i >> 4, c4 = i & 15;
            *(float4*)&ws[kk * 64 + 4 * c4] = *(const float4*)&W[(kc + kk) * 64 + 4 * c4];
        }
        for (int i = tid; i < 64 * (KC / 4); i += 256) {
            int r = i / (KC / 4), q = i % (KC / 4);
            float4 v = make_float4(0.f, 0.f, 0.f, 0.f);
            int row = row0 + r;
            if (row < n) v = *(const float4*)&X[(size_t)row * K + kc + 4 * q];
            *(float4*)&xs[r * XS + 4 * q] = v;
        }
        __syncthreads();

        for (int q = 0; q < KC / 4; q++) {
            float4 xv[4];
#pragma unroll
            for (int r = 0; r < 4; r++)
                xv[r] = *(const float4*)&xs[(ty + 16 * r) * XS + 4 * q];
#pragma unroll
            for (int kk = 0; kk < 4; kk++) {
                float4 wv = *(const float4*)&ws[(4 * q + kk) * 64 + 4 * tx];
#pragma unroll
                for (int r = 0; r < 4; r++) {
                    float xval = (kk == 0) ? xv[r].x : (kk == 1) ? xv[r].y
                               : (kk == 2) ? xv[r].z : xv[r].w;
                    acc[r][0] = fmaf(xval, wv.x, acc[r][0]);
                    acc[r][1] = fmaf(xval, wv.y, acc[r][1]);
                    acc[r][2] = fmaf(xval, wv.z, acc[r][2]);
                    acc[r][3] = fmaf(xval, wv.w, acc[r][3]);
                }
            }
        }
        __syncthreads();
    }

#pragma unroll
    for (int r = 0; r < 4; r++) {
        int row = row0 + ty + 16 * r;
        if (row < n) {
            float d = dinv[row];
            float4 o;
            o.x = acc[r][0] * d; o.y = acc[r][1] * d;
            o.z = acc[r][2] * d; o.w = acc[r][3] * d;
            *(float4*)&Y[(size_t)row * 64 + 4 * tx] = o;
        }
    }
}

// Per-wg: replay private edge list, gather y[src] rows (lane=feature),
// accumulate into LDS tile via ds_add_f32 (stride 64 -> 2 lanes/bank, free).
__global__ __launch_bounds__(BLK) void k_aggf(const float* __restrict__ y,
                                              const unsigned* __restrict__ elist,
                                              const int* __restrict__ ecnt,
                                              const float* __restrict__ dinv,
                                              const float* __restrict__ bias,
                                              float* __restrict__ out, int n) {
    __shared__ float acc[SRANGE * 64];  // 50176 B
    const int tid = threadIdx.x;
    const int lane = tid & 63;
    const int wave = tid >> 6;          // 0..15
    const int A = blockIdx.x * SRANGE;
    for (int i = tid; i < SRANGE * 64; i += BLK) acc[i] = 0.f;
    __syncthreads();

    const int m = ecnt[blockIdx.x];
    const unsigned* el = elist + (size_t)blockIdx.x * ECAP;
    for (int base = wave * 64; base < m; base += 16 * 64) {
        int idx = base + lane;
        unsigned uv = (idx < m) ? el[idx] : 0u;
        int count = m - base; if (count > 64) count = 64;
        int l = 0;
        for (; l + 4 <= count; l += 4) {
            unsigned u0 = __shfl(uv, l);
            unsigned u1 = __shfl(uv, l + 1);
            unsigned u2 = __shfl(uv, l + 2);
            unsigned u3 = __shfl(uv, l + 3);
            float v0 = y[(u0 & 0xffffu) * 64 + lane];
            float v1 = y[(u1 & 0xffffu) * 64 + lane];
            float v2 = y[(u2 & 0xffffu) * 64 + lane];
            float v3 = y[(u3 & 0xffffu) * 64 + lane];
            atomicAdd(&acc[((u0 >> 16) - A) * 64 + lane], v0);
            atomicAdd(&acc[((u1 >> 16) - A) * 64 + lane], v1);
            atomicAdd(&acc[((u2 >> 16) - A) * 64 + lane], v2);
            atomicAdd(&acc[((u3 >> 16) - A) * 64 + lane], v3);
        }
        for (; l < count; l++) {
            unsigned u0 = __shfl(uv, l);
            float v0 = y[(u0 & 0xffffu) * 64 + lane];
            atomicAdd(&acc[((u0 >> 16) - A) * 64 + lane], v0);
        }
    }
    __syncthreads();

    for (int i = tid; i < SRANGE * 64; i += BLK) {
        int r = i >> 6, c = i & 63;
        int row = A + r;
        if (row < n) {
            float dv = dinv[row];
            float v = fmaf(dv, acc[i] + y[(size_t)row * 64 + c], bias[c]);
            out[(size_t)row * 64 + c] = fmaxf(v, 0.f);
        }
    }
}

// out[i][c] = sum_k h[i][k] * Wfc[k][c] + bfc[c],  c < 12
__global__ __launch_bounds__(256) void k_fc(const float* __restrict__ h,
                                            const float* __restrict__ Wfc,
                                            const float* __restrict__ bfc,
                                            float* __restrict__ out, int n) {
    __shared__ float hs[64 * 64];
    __shared__ float wf[64 * 12];
    __shared__ float bf[12];
    int tid = threadIdx.x;
    int node0 = blockIdx.x * 64;
    for (int i = tid; i < 64 * 12; i += 256) wf[i] = Wfc[i];
    if (tid < 12) bf[tid] = bfc[tid];
    for (int f = tid; f < 1024; f += 256) {
        int r = f >> 4, c4 = f & 15;
        float4 v = make_float4(0.f, 0.f, 0.f, 0.f);
        if (node0 + r < n) v = *(const float4*)&h[(size_t)(node0 + r) * 64 + 4 * c4];
        *(float4*)&hs[r * 64 + 4 * c4] = v;
    }
    __syncthreads();
    for (int o = tid; o < 64 * 12; o += 256) {
        int r = o / 12, c = o % 12;
        if (node0 + r >= n) continue;
        float acc = bf[c];
        for (int k = 0; k < 64; k++) acc = fmaf(hs[r * 64 + k], wf[k * 12 + c], acc);
        out[(size_t)(node0 + r) * 12 + c] = acc;
    }
}

extern "C" void kernel_launch(void* const* d_in, const int* in_sizes, int n_in,
                              void* d_out, int out_size, void* d_ws, size_t ws_size,
                              hipStream_t stream) {
    const float* x   = (const float*)d_in[0];
    const int*   ei  = (const int*)d_in[1];
    const float* W1  = (const float*)d_in[2];
    const float* b1  = (const float*)d_in[3];
    const float* W2  = (const float*)d_in[4];
    const float* b2  = (const float*)d_in[5];
    const float* Wfc = (const float*)d_in[6];
    const float* bfc = (const float*)d_in[7];
    float* out = (float*)d_out;

    const int n = in_sizes[0] / 128;   // 50000
    const int E = in_sizes[1] / 2;     // 800000
    const int* src = ei;
    const int* dst = ei + E;

    // workspace layout (256B-aligned chunks), total ~33.2 MB
    char* w = (char*)d_ws;
    unsigned* ep    = (unsigned*)w;  w += (size_t)((E + 63) / 64) * 64 * 4;   // 3.2 MB
    unsigned* elist = (unsigned*)w;  w += (size_t)NWG * ECAP * 4;             // 4.0 MB
    int* ecnt       = (int*)w;       w += 256 * 4;
    float* dinv     = (float*)w;     w += (size_t)((n + 63) / 64) * 64 * 4;   // 200 KB
    float* y        = (float*)w;     w += (size_t)n * 64 * 4;                 // 12.8 MB
    float* h        = (float*)w;                                              // 12.8 MB

    k_pack <<<dim3((E + 255) / 256), dim3(256), 0, stream>>>(src, dst, ep, E);
    k_build<<<dim3(NWG), dim3(BLK), 0, stream>>>(ep, elist, ecnt, dinv, n, E);
    k_gemm<128><<<dim3((n + 63) / 64), dim3(256), 0, stream>>>(x, W1, dinv, y, n);
    k_aggf<<<dim3(NWG), dim3(BLK), 0, stream>>>(y, elist, ecnt, dinv, b1, h, n);
    k_gemm<64><<<dim3((n + 63) / 64), dim3(256), 0, stream>>>(h, W2, dinv, y, n);
    k_aggf<<<dim3(NWG), dim3(BLK), 0, stream>>>(y, elist, ecnt, dinv, b2, h, n);
    k_fc   <<<dim3((n + 63) / 64), dim3(256), 0, stream>>>(h, Wfc, bfc, out, n);
}

// Round 5
// 257.547 us; speedup vs baseline: 3.0687x; 3.0687x over previous
//
#include <hip/hip_runtime.h>

// GCN: h1 = relu(agg(x@W1)); h2 = relu(agg(h1@W2)); out = h2@Wfc + bfc
// out_i = relu( dinv_i * (sum_{j in N(i)} y_j + y_i) + b ),  y = (x@W)*dinv[:,None]
// dinv_i = rsqrt(indeg_i + 1).
// Round-2 skeleton (best so far): CAP-padded CSR via cursor atomics (zero+fill),
// per-node-wave gather agg. Round-5: ushort CSR + 16-deep MLP in k_agg.
// Lessons: R3: 800k device atomics ~= 45-50us regardless of payload (LLC atomic
// ceiling). R4: owner-computes/LDS-atomic/shfl agg = 6x WORSE (TLP collapse).

#define CAP 64   // max in-degree capacity (Poisson(16), max over 50k ~ 35)

typedef unsigned short u16;

__global__ __launch_bounds__(256) void k_zero(int* __restrict__ p, int n) {
    int i = blockIdx.x * 256 + threadIdx.x;
    if (i < n) p[i] = 0;
}

__global__ __launch_bounds__(256) void k_fill(const int* __restrict__ src,
                                              const int* __restrict__ dst,
                                              int* __restrict__ cursor,
                                              u16* __restrict__ csr, int E) {
    int e = blockIdx.x * 256 + threadIdx.x;
    if (e >= E) return;
    int d = dst[e];
    int p = atomicAdd(&cursor[d], 1);
    if (p < CAP) csr[d * CAP + p] = (u16)src[e];
}

// Y[row][c] = dinv[row] * sum_k X[row][k] * W[k][c];  64 output cols.
// 64-row x 64-col tile, 256 threads, 4x4 register tile per thread.
template <int K>
__global__ __launch_bounds__(256) void k_gemm(const float* __restrict__ X,
                                              const float* __restrict__ W,
                                              const int* __restrict__ cnt,
                                              float* __restrict__ Y, int n) {
    constexpr int KC = 64;
    constexpr int XS = KC + 4;
    __shared__ float ws[KC * 64];
    __shared__ float xs[64 * XS];
    const int tid = threadIdx.x;
    const int tx = tid & 15;
    const int ty = tid >> 4;
    const int row0 = blockIdx.x * 64;

    float acc[4][4];
#pragma unroll
    for (int r = 0; r < 4; r++)
#pragma unroll
        for (int c = 0; c < 4; c++) acc[r][c] = 0.f;

    for (int kc = 0; kc < K; kc += KC) {
        for (int i = tid; i < KC * 16; i += 256) {
            int kk = i >> 4, c4 = i & 15;
            *(float4*)&ws[kk * 64 + 4 * c4] = *(const float4*)&W[(kc + kk) * 64 + 4 * c4];
        }
        for (int i = tid; i < 64 * (KC / 4); i += 256) {
            int r = i / (KC / 4), q = i % (KC / 4);
            float4 v = make_float4(0.f, 0.f, 0.f, 0.f);
            int row = row0 + r;
            if (row < n) v = *(const float4*)&X[(size_t)row * K + kc + 4 * q];
            *(float4*)&xs[r * XS + 4 * q] = v;
        }
        __syncthreads();

        for (int q = 0; q < KC / 4; q++) {
            float4 xv[4];
#pragma unroll
            for (int r = 0; r < 4; r++)
                xv[r] = *(const float4*)&xs[(ty + 16 * r) * XS + 4 * q];
#pragma unroll
            for (int kk = 0; kk < 4; kk++) {
                float4 wv = *(const float4*)&ws[(4 * q + kk) * 64 + 4 * tx];
#pragma unroll
                for (int r = 0; r < 4; r++) {
                    float xval = (kk == 0) ? xv[r].x : (kk == 1) ? xv[r].y
                               : (kk == 2) ? xv[r].z : xv[r].w;
                    acc[r][0] = fmaf(xval, wv.x, acc[r][0]);
                    acc[r][1] = fmaf(xval, wv.y, acc[r][1]);
                    acc[r][2] = fmaf(xval, wv.z, acc[r][2]);
                    acc[r][3] = fmaf(xval, wv.w, acc[r][3]);
                }
            }
        }
        __syncthreads();
    }

#pragma unroll
    for (int r = 0; r < 4; r++) {
        int row = row0 + ty + 16 * r;
        if (row < n) {
            float d = rsqrtf((float)cnt[row] + 1.0f);
            float4 o;
            o.x = acc[r][0] * d; o.y = acc[r][1] * d;
            o.z = acc[r][2] * d; o.w = acc[r][3] * d;
            *(float4*)&Y[(size_t)row * 64 + 4 * tx] = o;
        }
    }
}

// out[i][c] = relu( dinv_i * (y[i][c] + sum_j y[j][c]) + bias[c] )
// one wave per node, lane = feature channel; 16-deep unrolled gather (16
// outstanding 256B row loads per wave). Indices: ushort CSR read as uint4.
__global__ __launch_bounds__(256) void k_agg(const float* __restrict__ y,
                                             const u16* __restrict__ csr,
                                             const int* __restrict__ cnt,
                                             const float* __restrict__ bias,
                                             float* __restrict__ out, int n) {
    int node = (blockIdx.x * 256 + threadIdx.x) >> 6;
    int lane = threadIdx.x & 63;
    if (node >= n) return;
    int deg_raw = cnt[node];
    int deg = deg_raw > CAP ? CAP : deg_raw;
    const u16* lst = csr + node * CAP;
    float acc = y[node * 64 + lane];  // self term
    int i = 0;
    for (; i + 16 <= deg; i += 16) {
        uint4 qa = *(const uint4*)(lst + i);       // ushorts i..i+7
        uint4 qb = *(const uint4*)(lst + i + 8);   // ushorts i+8..i+15
        float v0  = y[(qa.x & 0xffffu) * 64 + lane];
        float v1  = y[(qa.x >> 16)     * 64 + lane];
        float v2  = y[(qa.y & 0xffffu) * 64 + lane];
        float v3  = y[(qa.y >> 16)     * 64 + lane];
        float v4  = y[(qa.z & 0xffffu) * 64 + lane];
        float v5  = y[(qa.z >> 16)     * 64 + lane];
        float v6  = y[(qa.w & 0xffffu) * 64 + lane];
        float v7  = y[(qa.w >> 16)     * 64 + lane];
        float v8  = y[(qb.x & 0xffffu) * 64 + lane];
        float v9  = y[(qb.x >> 16)     * 64 + lane];
        float v10 = y[(qb.y & 0xffffu) * 64 + lane];
        float v11 = y[(qb.y >> 16)     * 64 + lane];
        float v12 = y[(qb.z & 0xffffu) * 64 + lane];
        float v13 = y[(qb.z >> 16)     * 64 + lane];
        float v14 = y[(qb.w & 0xffffu) * 64 + lane];
        float v15 = y[(qb.w >> 16)     * 64 + lane];
        acc += (((v0 + v1) + (v2 + v3)) + ((v4 + v5) + (v6 + v7)))
             + (((v8 + v9) + (v10 + v11)) + ((v12 + v13) + (v14 + v15)));
    }
    if (i + 8 <= deg) {
        uint4 qa = *(const uint4*)(lst + i);
        float v0 = y[(qa.x & 0xffffu) * 64 + lane];
        float v1 = y[(qa.x >> 16)     * 64 + lane];
        float v2 = y[(qa.y & 0xffffu) * 64 + lane];
        float v3 = y[(qa.y >> 16)     * 64 + lane];
        float v4 = y[(qa.z & 0xffffu) * 64 + lane];
        float v5 = y[(qa.z >> 16)     * 64 + lane];
        float v6 = y[(qa.w & 0xffffu) * 64 + lane];
        float v7 = y[(qa.w >> 16)     * 64 + lane];
        acc += ((v0 + v1) + (v2 + v3)) + ((v4 + v5) + (v6 + v7));
        i += 8;
    }
    if (i + 4 <= deg) {
        uint2 qa = *(const uint2*)(lst + i);
        float v0 = y[(qa.x & 0xffffu) * 64 + lane];
        float v1 = y[(qa.x >> 16)     * 64 + lane];
        float v2 = y[(qa.y & 0xffffu) * 64 + lane];
        float v3 = y[(qa.y >> 16)     * 64 + lane];
        acc += (v0 + v1) + (v2 + v3);
        i += 4;
    }
    for (; i < deg; i++) acc += y[lst[i] * 64 + lane];
    float d = rsqrtf((float)deg_raw + 1.0f);
    float v = fmaf(d, acc, bias[lane]);
    out[node * 64 + lane] = fmaxf(v, 0.f);
}

// out[i][c] = sum_k h[i][k] * Wfc[k][c] + bfc[c],  c < 12
__global__ __launch_bounds__(256) void k_fc(const float* __restrict__ h,
                                            const float* __restrict__ Wfc,
                                            const float* __restrict__ bfc,
                                            float* __restrict__ out, int n) {
    __shared__ float hs[64 * 64];
    __shared__ float wf[64 * 12];
    __shared__ float bf[12];
    int tid = threadIdx.x;
    int node0 = blockIdx.x * 64;
    for (int i = tid; i < 64 * 12; i += 256) wf[i] = Wfc[i];
    if (tid < 12) bf[tid] = bfc[tid];
    for (int f = tid; f < 1024; f += 256) {
        int r = f >> 4, c4 = f & 15;
        float4 v = make_float4(0.f, 0.f, 0.f, 0.f);
        if (node0 + r < n) v = *(const float4*)&h[(size_t)(node0 + r) * 64 + 4 * c4];
        *(float4*)&hs[r * 64 + 4 * c4] = v;
    }
    __syncthreads();
    for (int o = tid; o < 64 * 12; o += 256) {
        int r = o / 12, c = o % 12;
        if (node0 + r >= n) continue;
        float acc = bf[c];
        for (int k = 0; k < 64; k++) acc = fmaf(hs[r * 64 + k], wf[k * 12 + c], acc);
        out[(size_t)(node0 + r) * 12 + c] = acc;
    }
}

extern "C" void kernel_launch(void* const* d_in, const int* in_sizes, int n_in,
                              void* d_out, int out_size, void* d_ws, size_t ws_size,
                              hipStream_t stream) {
    const float* x   = (const float*)d_in[0];
    const int*   ei  = (const int*)d_in[1];
    const float* W1  = (const float*)d_in[2];
    const float* b1  = (const float*)d_in[3];
    const float* W2  = (const float*)d_in[4];
    const float* b2  = (const float*)d_in[5];
    const float* Wfc = (const float*)d_in[6];
    const float* bfc = (const float*)d_in[7];
    float* out = (float*)d_out;

    const int n = in_sizes[0] / 128;   // 50000
    const int E = in_sizes[1] / 2;     // 800000
    const int* src = ei;
    const int* dst = ei + E;

    // workspace layout (256B-aligned chunks): cursor 200KB, csr 6.4MB, y/h 12.8MB
    char* w = (char*)d_ws;
    int* cursor = (int*)w;  w += (size_t)((n + 63) / 64) * 64 * 4;
    u16* csr    = (u16*)w;  w += (size_t)n * CAP * 2;
    float* y    = (float*)w; w += (size_t)n * 64 * 4;
    float* h    = (float*)w;

    k_zero<<<dim3((n + 255) / 256), dim3(256), 0, stream>>>(cursor, n);
    k_fill<<<dim3((E + 255) / 256), dim3(256), 0, stream>>>(src, dst, cursor, csr, E);
    k_gemm<128><<<dim3((n + 63) / 64), dim3(256), 0, stream>>>(x, W1, cursor, y, n);
    k_agg<<<dim3((n + 3) / 4), dim3(256), 0, stream>>>(y, csr, cursor, b1, h, n);
    k_gemm<64><<<dim3((n + 63) / 64), dim3(256), 0, stream>>>(h, W2, cursor, y, n);
    k_agg<<<dim3((n + 3) / 4), dim3(256), 0, stream>>>(y, csr, cursor, b2, h, n);
    k_fc<<<dim3((n + 63) / 64), dim3(256), 0, stream>>>(h, Wfc, bfc, out, n);
}

// Round 6
// 256.078 us; speedup vs baseline: 3.0863x; 1.0057x over previous
//
#include <hip/hip_runtime.h>

// GCN: h1 = relu(agg(x@W1)); h2 = relu(agg(h1@W2)); out = h2@Wfc + bfc
// out_i = relu( dinv_i * (sum_{j in N(i)} y_j + y_i) + b ),  y = (x@W)*dinv[:,None]
// R6: CSR built with ZERO device-scope atomics (R3/R5 lesson: 800k random
// atomics+scatter = ~52us floor = one 64B line round-trip per edge).
// Pipeline: pack+blockhist -> scan -> bucket-scatter (LDS-ranked) ->
// per-bucket LDS CSR build (coalesced writes). Buckets = dst>>8 (196).

#define CAP   64        // per-node CSR capacity (Poisson(16), max ~35)
#define NBUK  196       // buckets: dst>>8, dst < 50176
#define ET    2048      // edges per block in pack/scatter
#define NB    391       // ceil(800000/2048)

typedef unsigned short u16;

// pack edges, per-block bucket histogram (plain stores, no device atomics)
__global__ __launch_bounds__(256) void k_pack(const int* __restrict__ src,
                                              const int* __restrict__ dst,
                                              unsigned* __restrict__ ep,
                                              int* __restrict__ blkcnt, int E) {
    __shared__ int hist[NBUK];
    const int tid = threadIdx.x, blk = blockIdx.x;
    for (int i = tid; i < NBUK; i += 256) hist[i] = 0;
    __syncthreads();
    const int e0 = blk * ET;
#pragma unroll
    for (int j = 0; j < ET / 256; j++) {
        int e = e0 + j * 256 + tid;
        if (e < E) {
            unsigned d = (unsigned)dst[e];
            unsigned s = (unsigned)src[e];
            ep[e] = (d << 16) | s;
            atomicAdd(&hist[d >> 8], 1);   // LDS atomic
        }
    }
    __syncthreads();
    for (int b = tid; b < NBUK; b += 256) blkcnt[b * NB + blk] = hist[b];
}

// single block: per-bucket totals -> exclusive bucket bases; rewrite blkcnt
// to per-block global bases within each bucket. bbase[NBUK] = E.
__global__ __launch_bounds__(256) void k_scanb(int* __restrict__ blkcnt,
                                               int* __restrict__ bbase, int E) {
    __shared__ int s[256];
    const int b = threadIdx.x;
    int sum = 0;
    if (b < NBUK)
        for (int k = 0; k < NB; k++) sum += blkcnt[b * NB + k];
    s[b] = sum;
    __syncthreads();
#pragma unroll
    for (int d = 1; d < 256; d <<= 1) {
        int t = (b >= d) ? s[b - d] : 0;
        __syncthreads();
        s[b] += t;
        __syncthreads();
    }
    int base = s[b] - sum;  // exclusive
    if (b < NBUK) {
        bbase[b] = base;
        int run = base;
        for (int k = 0; k < NB; k++) {
            int c = blkcnt[b * NB + k];
            blkcnt[b * NB + k] = run;
            run += c;
        }
    }
    if (b == 0) bbase[NBUK] = E;
}

// scatter packed edges into bucket-grouped array eb. Rank via LDS cursors
// seeded with this block's global base per bucket. No device atomics.
__global__ __launch_bounds__(256) void k_scatter(const unsigned* __restrict__ ep,
                                                 const int* __restrict__ blkcnt,
                                                 unsigned* __restrict__ eb, int E) {
    __shared__ int cur[NBUK];
    const int tid = threadIdx.x, blk = blockIdx.x;
    for (int i = tid; i < NBUK; i += 256) cur[i] = blkcnt[i * NB + blk];
    __syncthreads();
    const int e0 = blk * ET;
#pragma unroll
    for (int j = 0; j < ET / 256; j++) {
        int e = e0 + j * 256 + tid;
        if (e < E) {
            unsigned u = ep[e];
            int p = atomicAdd(&cur[u >> 24], 1);   // LDS atomic (bucket = dst>>8)
            eb[p] = u;
        }
    }
}

// one wg per bucket: build CAP-padded ushort CSR rows for its 256 nodes in
// LDS, then write csr + cnt fully coalesced.
__global__ __launch_bounds__(1024) void k_buildb(const unsigned* __restrict__ eb,
                                                 const int* __restrict__ bbase,
                                                 u16* __restrict__ csr,
                                                 int* __restrict__ cnt, int n) {
    __shared__ u16 lcsr[256 * CAP];   // 32 KB
    __shared__ int cur[256];
    const int tid = threadIdx.x, b = blockIdx.x;
    if (tid < 256) cur[tid] = 0;
    __syncthreads();
    const int e0 = bbase[b], e1 = bbase[b + 1];
    for (int e = e0 + tid; e < e1; e += 1024) {
        unsigned u = eb[e];
        int ld = (int)((u >> 16) & 255u);
        int p = atomicAdd(&cur[ld], 1);           // LDS atomic
        if (p < CAP) lcsr[ld * CAP + p] = (u16)(u & 0xffffu);
    }
    __syncthreads();
    // coalesced writes: 256 rows x 64 u16 = 32KB; pad unused slots with 0
    const int node0 = b * 256;
    for (int i = tid; i < 256 * CAP / 8; i += 1024) {   // uint4 = 8 u16
        int r = i / (CAP / 8), q = i % (CAP / 8);
        int c = cur[r] < CAP ? cur[r] : CAP;
        // zero slots >= c so agg's padded reads are harmless (agg clamps by cnt anyway)
        uint4 v = *(uint4*)&lcsr[r * CAP + q * 8];
        if (q * 8 >= c) v = make_uint4(0, 0, 0, 0);
        *(uint4*)&csr[(size_t)(node0 + r) * CAP + q * 8] = v;
    }
    if (tid < 256 && node0 + tid < n) cnt[node0 + tid] = cur[tid];
}

// Y[row][c] = dinv[row] * sum_k X[row][k] * W[k][c];  64 output cols.
template <int K>
__global__ __launch_bounds__(256) void k_gemm(const float* __restrict__ X,
                                              const float* __restrict__ W,
                                              const int* __restrict__ cnt,
                                              float* __restrict__ Y, int n) {
    constexpr int KC = 64;
    constexpr int XS = KC + 4;
    __shared__ float ws[KC * 64];
    __shared__ float xs[64 * XS];
    const int tid = threadIdx.x;
    const int tx = tid & 15;
    const int ty = tid >> 4;
    const int row0 = blockIdx.x * 64;

    float acc[4][4];
#pragma unroll
    for (int r = 0; r < 4; r++)
#pragma unroll
        for (int c = 0; c < 4; c++) acc[r][c] = 0.f;

    for (int kc = 0; kc < K; kc += KC) {
        for (int i = tid; i < KC * 16; i += 256) {
            int kk = i >> 4, c4 = i & 15;
            *(float4*)&ws[kk * 64 + 4 * c4] = *(const float4*)&W[(kc + kk) * 64 + 4 * c4];
        }
        for (int i = tid; i < 64 * (KC / 4); i += 256) {
            int r = i / (KC / 4), q = i % (KC / 4);
            float4 v = make_float4(0.f, 0.f, 0.f, 0.f);
            int row = row0 + r;
            if (row < n) v = *(const float4*)&X[(size_t)row * K + kc + 4 * q];
            *(float4*)&xs[r * XS + 4 * q] = v;
        }
        __syncthreads();

        for (int q = 0; q < KC / 4; q++) {
            float4 xv[4];
#pragma unroll
            for (int r = 0; r < 4; r++)
                xv[r] = *(const float4*)&xs[(ty + 16 * r) * XS + 4 * q];
#pragma unroll
            for (int kk = 0; kk < 4; kk++) {
                float4 wv = *(const float4*)&ws[(4 * q + kk) * 64 + 4 * tx];
#pragma unroll
                for (int r = 0; r < 4; r++) {
                    float xval = (kk == 0) ? xv[r].x : (kk == 1) ? xv[r].y
                               : (kk == 2) ? xv[r].z : xv[r].w;
                    acc[r][0] = fmaf(xval, wv.x, acc[r][0]);
                    acc[r][1] = fmaf(xval, wv.y, acc[r][1]);
                    acc[r][2] = fmaf(xval, wv.z, acc[r][2]);
                    acc[r][3] = fmaf(xval, wv.w, acc[r][3]);
                }
            }
        }
        __syncthreads();
    }

#pragma unroll
    for (int r = 0; r < 4; r++) {
        int row = row0 + ty + 16 * r;
        if (row < n) {
            float d = rsqrtf((float)cnt[row] + 1.0f);
            float4 o;
            o.x = acc[r][0] * d; o.y = acc[r][1] * d;
            o.z = acc[r][2] * d; o.w = acc[r][3] * d;
            *(float4*)&Y[(size_t)row * 64 + 4 * tx] = o;
        }
    }
}

// out[i][c] = relu( dinv_i * (y[i][c] + sum_j y[j][c]) + bias[c] )
// one wave per node, lane = feature; 16-deep unrolled gather.
__global__ __launch_bounds__(256) void k_agg(const float* __restrict__ y,
                                             const u16* __restrict__ csr,
                                             const int* __restrict__ cnt,
                                             const float* __restrict__ bias,
                                             float* __restrict__ out, int n) {
    int node = (blockIdx.x * 256 + threadIdx.x) >> 6;
    int lane = threadIdx.x & 63;
    if (node >= n) return;
    int deg_raw = cnt[node];
    int deg = deg_raw > CAP ? CAP : deg_raw;
    const u16* lst = csr + node * CAP;
    float acc = y[node * 64 + lane];  // self term
    int i = 0;
    for (; i + 16 <= deg; i += 16) {
        uint4 qa = *(const uint4*)(lst + i);
        uint4 qb = *(const uint4*)(lst + i + 8);
        float v0  = y[(qa.x & 0xffffu) * 64 + lane];
        float v1  = y[(qa.x >> 16)     * 64 + lane];
        float v2  = y[(qa.y & 0xffffu) * 64 + lane];
        float v3  = y[(qa.y >> 16)     * 64 + lane];
        float v4  = y[(qa.z & 0xffffu) * 64 + lane];
        float v5  = y[(qa.z >> 16)     * 64 + lane];
        float v6  = y[(qa.w & 0xffffu) * 64 + lane];
        float v7  = y[(qa.w >> 16)     * 64 + lane];
        float v8  = y[(qb.x & 0xffffu) * 64 + lane];
        float v9  = y[(qb.x >> 16)     * 64 + lane];
        float v10 = y[(qb.y & 0xffffu) * 64 + lane];
        float v11 = y[(qb.y >> 16)     * 64 + lane];
        float v12 = y[(qb.z & 0xffffu) * 64 + lane];
        float v13 = y[(qb.z >> 16)     * 64 + lane];
        float v14 = y[(qb.w & 0xffffu) * 64 + lane];
        float v15 = y[(qb.w >> 16)     * 64 + lane];
        acc += (((v0 + v1) + (v2 + v3)) + ((v4 + v5) + (v6 + v7)))
             + (((v8 + v9) + (v10 + v11)) + ((v12 + v13) + (v14 + v15)));
    }
    if (i + 8 <= deg) {
        uint4 qa = *(const uint4*)(lst + i);
        float v0 = y[(qa.x & 0xffffu) * 64 + lane];
        float v1 = y[(qa.x >> 16)     * 64 + lane];
        float v2 = y[(qa.y & 0xffffu) * 64 + lane];
        float v3 = y[(qa.y >> 16)     * 64 + lane];
        float v4 = y[(qa.z & 0xffffu) * 64 + lane];
        float v5 = y[(qa.z >> 16)     * 64 + lane];
        float v6 = y[(qa.w & 0xffffu) * 64 + lane];
        float v7 = y[(qa.w >> 16)     * 64 + lane];
        acc += ((v0 + v1) + (v2 + v3)) + ((v4 + v5) + (v6 + v7));
        i += 8;
    }
    if (i + 4 <= deg) {
        uint2 qa = *(const uint2*)(lst + i);
        float v0 = y[(qa.x & 0xffffu) * 64 + lane];
        float v1 = y[(qa.x >> 16)     * 64 + lane];
        float v2 = y[(qa.y & 0xffffu) * 64 + lane];
        float v3 = y[(qa.y >> 16)     * 64 + lane];
        acc += (v0 + v1) + (v2 + v3);
        i += 4;
    }
    for (; i < deg; i++) acc += y[lst[i] * 64 + lane];
    float d = rsqrtf((float)deg_raw + 1.0f);
    float v = fmaf(d, acc, bias[lane]);
    out[node * 64 + lane] = fmaxf(v, 0.f);
}

// out[i][c] = sum_k h[i][k] * Wfc[k][c] + bfc[c],  c < 12
__global__ __launch_bounds__(256) void k_fc(const float* __restrict__ h,
                                            const float* __restrict__ Wfc,
                                            const float* __restrict__ bfc,
                                            float* __restrict__ out, int n) {
    __shared__ float hs[64 * 64];
    __shared__ float wf[64 * 12];
    __shared__ float bf[12];
    int tid = threadIdx.x;
    int node0 = blockIdx.x * 64;
    for (int i = tid; i < 64 * 12; i += 256) wf[i] = Wfc[i];
    if (tid < 12) bf[tid] = bfc[tid];
    for (int f = tid; f < 1024; f += 256) {
        int r = f >> 4, c4 = f & 15;
        float4 v = make_float4(0.f, 0.f, 0.f, 0.f);
        if (node0 + r < n) v = *(const float4*)&h[(size_t)(node0 + r) * 64 + 4 * c4];
        *(float4*)&hs[r * 64 + 4 * c4] = v;
    }
    __syncthreads();
    for (int o = tid; o < 64 * 12; o += 256) {
        int r = o / 12, c = o % 12;
        if (node0 + r >= n) continue;
        float acc = bf[c];
        for (int k = 0; k < 64; k++) acc = fmaf(hs[r * 64 + k], wf[k * 12 + c], acc);
        out[(size_t)(node0 + r) * 12 + c] = acc;
    }
}

extern "C" void kernel_launch(void* const* d_in, const int* in_sizes, int n_in,
                              void* d_out, int out_size, void* d_ws, size_t ws_size,
                              hipStream_t stream) {
    const float* x   = (const float*)d_in[0];
    const int*   ei  = (const int*)d_in[1];
    const float* W1  = (const float*)d_in[2];
    const float* b1  = (const float*)d_in[3];
    const float* W2  = (const float*)d_in[4];
    const float* b2  = (const float*)d_in[5];
    const float* Wfc = (const float*)d_in[6];
    const float* bfc = (const float*)d_in[7];
    float* out = (float*)d_out;

    const int n = in_sizes[0] / 128;   // 50000
    const int E = in_sizes[1] / 2;     // 800000
    const int* src = ei;
    const int* dst = ei + E;

    // workspace: ep 3.2MB, eb 3.2MB, blkcnt 306KB, bbase, cnt 200KB,
    // csr 6.4MB, y 12.8MB, h 12.8MB  (~39MB)
    char* w = (char*)d_ws;
    unsigned* ep  = (unsigned*)w;  w += (size_t)((E + 63) / 64) * 64 * 4;
    unsigned* eb  = (unsigned*)w;  w += (size_t)((E + 63) / 64) * 64 * 4;
    int* blkcnt   = (int*)w;       w += (size_t)NBUK * NB * 4 + 256;
    int* bbase    = (int*)w;       w += (NBUK + 64) * 4;
    int* cnt      = (int*)w;       w += (size_t)((n + 63) / 64) * 64 * 4;
    u16* csr      = (u16*)w;       w += (size_t)NBUK * 256 * CAP * 2;
    float* y      = (float*)w;     w += (size_t)n * 64 * 4;
    float* h      = (float*)w;

    k_pack   <<<dim3(NB), dim3(256), 0, stream>>>(src, dst, ep, blkcnt, E);
    k_scanb  <<<dim3(1), dim3(256), 0, stream>>>(blkcnt, bbase, E);
    k_scatter<<<dim3(NB), dim3(256), 0, stream>>>(ep, blkcnt, eb, E);
    k_buildb <<<dim3(NBUK), dim3(1024), 0, stream>>>(eb, bbase, csr, cnt, n);
    k_gemm<128><<<dim3((n + 63) / 64), dim3(256), 0, stream>>>(x, W1, cnt, y, n);
    k_agg    <<<dim3((n + 3) / 4), dim3(256), 0, stream>>>(y, csr, cnt, b1, h, n);
    k_gemm<64><<<dim3((n + 63) / 64), dim3(256), 0, stream>>>(h, W2, cnt, y, n);
    k_agg    <<<dim3((n + 3) / 4), dim3(256), 0, stream>>>(y, csr, cnt, b2, h, n);
    k_fc     <<<dim3((n + 63) / 64), dim3(256), 0, stream>>>(h, Wfc, bfc, out, n);
}